// Round 5
// baseline (6881.859 us; speedup 1.0000x reference)
//
#include <hip/hip_runtime.h>
#include <stdint.h>

#define B_   128
#define S_   256
#define I_   256
#define H_   1024
#define O_   256
#define BSO  (B_*S_*O_)

typedef unsigned short u16;
typedef unsigned int   u32;

using short8 = __attribute__((ext_vector_type(8))) short;   // 8 bf16 in 4 VGPRs
using float8 = __attribute__((ext_vector_type(8))) float;   // 8 fp32 in 8 VGPRs
using f32x4  = __attribute__((ext_vector_type(4))) float;

__device__ __forceinline__ float bf2f(u16 u) {
    return __uint_as_float(((u32)u) << 16);
}
__device__ __forceinline__ u16 f2bf(float f) {
    u32 x = __float_as_uint(f);
    x += 0x7FFFu + ((x >> 16) & 1u);   // RNE
    return (u16)(x >> 16);
}
// NaN-robust clamp (comparison-based)
__device__ __forceinline__ float clampf_(float x, float lo, float hi) {
    x = (x < hi) ? x : hi;
    x = (x > lo) ? x : lo;
    return x;
}
__device__ __forceinline__ float sigmoidf_(float x) {
    x = clampf_(x, -60.f, 60.f);
    return 1.0f / (1.0f + __expf(-x));
}
__device__ __forceinline__ float tanhf_(float x) {
    float x2 = clampf_(2.0f * x, -30.0f, 30.0f);
    float e = __expf(x2);
    return (e - 1.0f) / (e + 1.0f);
}

// generic scalar load -> float
__device__ __forceinline__ float loadf(const float* p) { return *p; }
__device__ __forceinline__ float loadf(const u16* p)   { return bf2f(*p); }

// 8-wide vector type per element type
template<typename T> struct V8S;
template<> struct V8S<u16>   { using t = short8; };
template<> struct V8S<float> { using t = float8; };

__device__ __forceinline__ short8 to_bf8(short8 v) { return v; }
__device__ __forceinline__ short8 to_bf8(float8 v) {
    short8 r;
    #pragma unroll
    for (int j = 0; j < 8; j++) r[j] = (short)f2bf(v[j]);
    return r;
}

// ---------------------------------------------------------------------------
// init: split h0 (B,L,H) fp32 into per-layer bf16 state buffers; zero backs
__global__ void init_h(const float* __restrict__ h0, u16* __restrict__ hA0, u16* __restrict__ hA1,
                       u16* __restrict__ hB0, u16* __restrict__ hB1)
{
    int idx = blockIdx.x * 256 + threadIdx.x;   // over B*H
    int b = idx >> 10, j = idx & 1023;
    hA0[idx] = f2bf(h0[b * 2048 + j]);
    hA1[idx] = f2bf(h0[b * 2048 + 1024 + j]);
    hB0[idx] = 0;
    hB1[idx] = 0;
}

// fp32 -> bf16 bulk convert
__global__ void cvt_bf(const float* __restrict__ in, u16* __restrict__ out, int n)
{
    int i = blockIdx.x * 256 + threadIdx.x;
    if (i < n) out[i] = f2bf(in[i]);
}

// ---------------------------------------------------------------------------
// scalar-gate projections: xz[m] = X[m,:]·Wz ; xr[m] = X[m,:]·Wr + br
template<typename XT>
__global__ __launch_bounds__(256, 4)
void proj_zr(const XT* __restrict__ X, const float* __restrict__ Wz,
             const float* __restrict__ Wr, const float* __restrict__ br,
             float* __restrict__ xz, float* __restrict__ xr, int K)
{
    const int lane = threadIdx.x & 63;
    const int wv   = threadIdx.x >> 6;
    const long m   = (long)blockIdx.x * 4 + wv;
    const XT* xp   = X + m * K;
    float az = 0.f, ar = 0.f;
    for (int i = lane; i < K; i += 64) {
        float xv = loadf(xp + i);
        az = fmaf(xv, Wz[i], az);
        ar = fmaf(xv, Wr[i], ar);
    }
    #pragma unroll
    for (int o = 1; o < 64; o <<= 1) { az += __shfl_xor(az, o); ar += __shfl_xor(ar, o); }
    if (lane == 0) {
        xz[m] = clampf_(az, -1e4f, 1e4f);
        xr[m] = clampf_(ar + br[0], -1e4f, 1e4f);
    }
}

// ---------------------------------------------------------------------------
// C[M,N] = A[M,K] · W[N,K]^T.  A: fp32 or bf16 (converted at LDS staging);
// W: fp32 (converted at LDS staging); accum fp32.
// MODE 0: store bf16. MODE 1: store fp32 sigmoid(val + bias[n]).
template<int MODE, typename AT>
__global__ __launch_bounds__(256, 2)
void gemm_bt(const AT* __restrict__ A, const float* __restrict__ W,
             const float* __restrict__ bias, void* __restrict__ Cv,
             int M, int N, int K)
{
    __shared__ alignas(16) u16 As[128 * 32];
    __shared__ alignas(16) u16 Ws[128 * 32];
    const int tid  = threadIdx.x;
    const int lane = tid & 63;
    const int wv   = tid >> 6;
    const int l15  = lane & 15;
    const int quad = lane >> 4;
    const int wm   = wv >> 1, wn = wv & 1;
    const long m0  = (long)blockIdx.y * 128;
    const long n0  = (long)blockIdx.x * 128;

    const int c0 = tid, c1 = tid + 256;
    const long ar0 = (m0 + (c0 >> 2)) * (long)K + (c0 & 3) * 8;
    const long ar1 = (m0 + (c1 >> 2)) * (long)K + (c1 & 3) * 8;
    const long wr0 = (n0 + (c0 >> 2)) * (long)K + (c0 & 3) * 8;
    const long wr1 = (n0 + (c1 >> 2)) * (long)K + (c1 & 3) * 8;

    f32x4 zero4 = {0.f, 0.f, 0.f, 0.f};
    f32x4 acc[4][4];
    #pragma unroll
    for (int i = 0; i < 4; i++)
        #pragma unroll
        for (int j = 0; j < 4; j++) acc[i][j] = zero4;

    typename V8S<AT>::t va0 = *(const typename V8S<AT>::t*)(A + ar0);
    typename V8S<AT>::t va1 = *(const typename V8S<AT>::t*)(A + ar1);
    float8 vw0 = *(const float8*)(W + wr0);
    float8 vw1 = *(const float8*)(W + wr1);

    for (int k0 = 0; k0 < K; k0 += 32) {
        __syncthreads();
        *(short8*)(As + c0 * 8) = to_bf8(va0);
        *(short8*)(As + c1 * 8) = to_bf8(va1);
        *(short8*)(Ws + c0 * 8) = to_bf8(vw0);
        *(short8*)(Ws + c1 * 8) = to_bf8(vw1);
        __syncthreads();
        int kn = k0 + 32;
        if (kn < K) {
            va0 = *(const typename V8S<AT>::t*)(A + ar0 + kn);
            va1 = *(const typename V8S<AT>::t*)(A + ar1 + kn);
            vw0 = *(const float8*)(W + wr0 + kn);
            vw1 = *(const float8*)(W + wr1 + kn);
        }
        short8 af[4], wf[4];
        #pragma unroll
        for (int i = 0; i < 4; i++)
            af[i] = *(const short8*)(As + (wm * 64 + i * 16 + l15) * 32 + quad * 8);
        #pragma unroll
        for (int j = 0; j < 4; j++)
            wf[j] = *(const short8*)(Ws + (wn * 64 + j * 16 + l15) * 32 + quad * 8);
        #pragma unroll
        for (int i = 0; i < 4; i++)
            #pragma unroll
            for (int j = 0; j < 4; j++)
                acc[i][j] = __builtin_amdgcn_mfma_f32_16x16x32_bf16(af[i], wf[j], acc[i][j], 0, 0, 0);
    }

    // epilogue: D col = lane&15 (n), row = quad*4+reg (m)
    #pragma unroll
    for (int i = 0; i < 4; i++) {
        #pragma unroll
        for (int j = 0; j < 4; j++) {
            int nn = (int)n0 + wn * 64 + j * 16 + l15;
            #pragma unroll
            for (int v = 0; v < 4; v++) {
                long mm = m0 + wm * 64 + i * 16 + quad * 4 + v;
                float val = acc[i][j][v];
                if (MODE == 1) {
                    ((float*)Cv)[mm * N + nn] = sigmoidf_(val + bias[nn]);
                } else {
                    ((u16*)Cv)[mm * N + nn] = f2bf(clampf_(val, -1e4f, 1e4f));
                }
            }
        }
    }
}

// ---------------------------------------------------------------------------
// ONE GRU timestep. grid = 128 blocks: blockIdx = g*16 + rb;
// g = batch group (16 batches), rb = column block (64 Whg rows).
// xgh: xg (bf16) read at t-slice, overwritten in place with hs (bf16).
// WhgBF: pre-converted bf16 Whg. Stream order is the only sync.
__global__ __launch_bounds__(256)
void gru_step(u16* __restrict__ xgh, const float* __restrict__ xz,
              const float* __restrict__ xr,
              const float* __restrict__ Whz, const float* __restrict__ Whr,
              const float* __restrict__ bhz, const u16* __restrict__ WhgBF,
              const float* __restrict__ bhg,
              const u16* __restrict__ hcur, u16* __restrict__ hnxt,
              float* __restrict__ hT, int t)
{
    __shared__ alignas(16) u16   hL[16 * 1040];
    __shared__ alignas(16) float wzL[H_], wrL[H_], bgL[H_];
    __shared__ alignas(16) float zF[16], rF[16];

    const int tid  = threadIdx.x;
    const int lane = tid & 63;
    const int wv   = tid >> 6;
    const int l15  = lane & 15;
    const int quad = lane >> 4;
    const int g    = blockIdx.x >> 4;         // batch group 0..7
    const int rb   = blockIdx.x & 15;         // column block 0..15
    const int m0   = g * 16;
    const int nw   = rb * 64 + wv * 16;       // wave's Whg row base

    for (int i = tid; i < H_; i += 256) {
        wzL[i] = Whz[i];
        wrL[i] = Whr[i];
        bgL[i] = bhg[i];
    }

    // stage h tile (16 batches x 1024) global -> LDS
    #pragma unroll
    for (int i = 0; i < 8; i++) {
        int cid  = tid + i * 256;
        int rrow = cid >> 7;
        int ccol = cid & 127;
        *(short8*)(hL + rrow * 1040 + ccol * 8) =
            *(const short8*)(hcur + (m0 + rrow) * H_ + ccol * 8);
    }
    __syncthreads();

    // z/r: each wave handles 4 batches; 64-lane reduction per batch
    const float bhzf = bhz[0];
    #pragma unroll
    for (int bb = 0; bb < 4; bb++) {
        int b = wv * 4 + bb;
        const u16* hb = hL + b * 1040;
        float sz = 0.f, sr = 0.f;
        for (int k = lane; k < H_; k += 64) {
            float hv = bf2f(hb[k]);
            sz = fmaf(hv, wzL[k], sz);
            sr = fmaf(hv, wrL[k], sr);
        }
        #pragma unroll
        for (int o = 1; o < 64; o <<= 1) { sz += __shfl_xor(sz, o); sr += __shfl_xor(sr, o); }
        if (lane == 0) {
            long mrow = (long)(m0 + b) * S_ + t;
            zF[b] = sigmoidf_(sz + xz[mrow] + bhzf);
            rF[b] = sigmoidf_(sr + xr[mrow]);
        }
    }
    __syncthreads();

    // h @ Whg^T for this wave's 16 output columns: 32 MFMAs over K=1024
    const u16* wgp = WhgBF + (long)(nw + l15) * H_ + quad * 8;
    f32x4 acc = {0.f, 0.f, 0.f, 0.f};
    #pragma unroll 8
    for (int kt = 0; kt < 32; kt++) {
        short8 bfrag = *(const short8*)(wgp + kt * 32);
        short8 a     = *(const short8*)(hL + l15 * 1040 + kt * 32 + quad * 8);
        acc = __builtin_amdgcn_mfma_f32_16x16x32_bf16(a, bfrag, acc, 0, 0, 0);
    }

    // gate + update + store (D: col=lane&15 -> jj, row=quad*4+v -> batch)
    const int jj = nw + l15;
    const float bg = bgL[jj];
    #pragma unroll
    for (int v = 0; v < 4; v++) {
        int  b    = quad * 4 + v;
        long row  = (long)(m0 + b) * S_ + t;
        float accv = clampf_(acc[v], -1e4f, 1e4f);
        float gpre = bf2f(xgh[row * H_ + jj]) + rF[b] * accv + bg;
        float gv   = tanhf_(gpre);
        float hold = clampf_(bf2f(hL[b * 1040 + jj]), -4.f, 4.f);
        float z    = zF[b];
        float hnew = clampf_(z * hold + (1.f - z) * gv, -4.f, 4.f);
        u16 hb = f2bf(hnew);
        hnxt[(m0 + b) * H_ + jj] = hb;
        xgh[row * H_ + jj]       = hb;              // in-place: xg slice -> hs slice
        if (t == S_ - 1) hT[(m0 + b) * (2 * H_) + jj] = hnew;
    }
}

// ---------------------------------------------------------------------------
extern "C" void kernel_launch(void* const* d_in, const int* in_sizes, int n_in,
                              void* d_out, int out_size, void* d_ws, size_t ws_size,
                              hipStream_t stream)
{
    (void)in_sizes; (void)n_in; (void)out_size;
    const float* x    = (const float*)d_in[0];
    const float* h0   = (const float*)d_in[1];
    const float* Wxz0 = (const float*)d_in[2];
    const float* Whz0 = (const float*)d_in[3];
    const float* bhz0 = (const float*)d_in[4];
    const float* Wxr0 = (const float*)d_in[5];
    const float* bxr0 = (const float*)d_in[6];
    const float* Whr0 = (const float*)d_in[7];
    const float* Wxg0 = (const float*)d_in[8];
    const float* Whg0 = (const float*)d_in[9];
    const float* bhg0 = (const float*)d_in[10];
    const float* Wxz1 = (const float*)d_in[11];
    const float* Whz1 = (const float*)d_in[12];
    const float* bhz1 = (const float*)d_in[13];
    const float* Wxr1 = (const float*)d_in[14];
    const float* bxr1 = (const float*)d_in[15];
    const float* Whr1 = (const float*)d_in[16];
    const float* Wxg1 = (const float*)d_in[17];
    const float* Whg1 = (const float*)d_in[18];
    const float* bhg1 = (const float*)d_in[19];
    const float* Why  = (const float*)d_in[20];
    const float* bhy  = (const float*)d_in[21];
    float* out = (float*)d_out;

    char* ws = (char*)d_ws;
    u16*   BUF_A = (u16*)(ws);                        // xg0 -> hs0 in place (64 MB)
    u16*   BUF_B = (u16*)(ws + 67108864);             // Whg0bf, then xg1 -> hs1 (64 MB)
    float* XZ    = (float*)(ws + 134217728);          // 128 KB
    float* XR    = (float*)(ws + 134348800);          // 128 KB
    u16*   HA0   = (u16*)(ws + 134479872);            // h state dbl buffers (bf16)
    u16*   HB0   = (u16*)(ws + 134742016);
    u16*   HA1   = (u16*)(ws + 135004160);
    u16*   HB1   = (u16*)(ws + 135266304);
    if (ws_size < (size_t)135528448) return;

    init_h<<<512, 256, 0, stream>>>(h0, HA0, HA1, HB0, HB1);

    const int M = B_ * S_;   // 32768

    // ---- layer 0 ----
    // Whg0 -> bf16, parked in BUF_B (dead region until gemm1 writes xg1)
    cvt_bf<<<(H_ * H_) / 256, 256, 0, stream>>>(Whg0, BUF_B, H_ * H_);
    proj_zr<float><<<M / 4, 256, 0, stream>>>(x, Wxz0, Wxr0, bxr0, XZ, XR, I_);
    gemm_bt<0, float><<<dim3(H_ / 128, M / 128), 256, 0, stream>>>(x, Wxg0, nullptr, BUF_A, M, H_, I_);
    {
        u16* hc = HA0; u16* hn = HB0;
        for (int t = 0; t < S_; t++) {
            gru_step<<<128, 256, 0, stream>>>(BUF_A, XZ, XR, Whz0, Whr0, bhz0, BUF_B, bhg0,
                                              hc, hn, out + (long)BSO, t);
            u16* tmp = hc; hc = hn; hn = tmp;
        }
    }

    // ---- layer 1 ----
    proj_zr<u16><<<M / 4, 256, 0, stream>>>(BUF_A, Wxz1, Wxr1, bxr1, XZ, XR, H_);
    gemm_bt<0, u16><<<dim3(H_ / 128, M / 128), 256, 0, stream>>>(BUF_A, Wxg1, nullptr, BUF_B, M, H_, H_);
    // Whg1 -> bf16, parked in BUF_A (hs0 dead after gemm1 + proj_zr1)
    cvt_bf<<<(H_ * H_) / 256, 256, 0, stream>>>(Whg1, BUF_A, H_ * H_);
    {
        u16* hc = HA1; u16* hn = HB1;
        for (int t = 0; t < S_; t++) {
            gru_step<<<128, 256, 0, stream>>>(BUF_B, XZ, XR, Whz1, Whr1, bhz1, BUF_A, bhg1,
                                              hc, hn, out + (long)BSO + H_, t);
            u16* tmp = hc; hc = hn; hn = tmp;
        }
    }

    // ---- output head: sigmoid(hs1 @ Why^T + bhy) -> (B,S,O) fp32 ----
    gemm_bt<1, u16><<<dim3(O_ / 128, M / 128), 256, 0, stream>>>(BUF_B, Why, bhy, (void*)out, M, O_, H_);
}